// Round 12
// baseline (73.025 us; speedup 1.0000x reference)
//
#include <hip/hip_runtime.h>
#include <stdint.h>

// NMU forward: y[b,o] = prod_d( clip(M[d,o],0,1)*x[b,d] + 1-clip(M[d,o],0,1) )
// B=16384, D=256, O=32, fp32.
//
// R12 = R11's compute layout + software-pipelined x staging.
// R11 post-mortem: cutting LDS-port broadcasts 4x was neutral -> the ~20 us
// kernel is phase-serialization (one-shot stage burst -> barrier -> compute),
// not port-bound. Fix: 4 tiles of 4 rows, register-transit double buffer:
//   issue tile t+1 global load -> compute tile t from LDS -> write t+1 ->
//   barrier. Only the first 4-row tile's latency is exposed; the rest
//   overlaps compute. Everything else (resident M = 16 named v2f, DPP
//   ds-lane reduction, partial merge epilogue) is R11's verified structure.

typedef float v2f __attribute__((ext_vector_type(2)));

constexpr int D = 256;
constexpr int O = 32;
constexpr int ROWS_PB = 16;          // rows per block -> 1024 blocks
constexpr int TR = 4;                // rows per tile
constexpr int NT = ROWS_PB / TR;     // 4 tiles

template <int CTRL>
__device__ __forceinline__ float dppmul(float v) {
    int i = __builtin_bit_cast(int, v);
    int p = __builtin_amdgcn_update_dpp(i, i, CTRL, 0xF, 0xF, false);
    return v * __builtin_bit_cast(float, p);
}
template <int CTRL>
__device__ __forceinline__ v2f dppmul2(v2f v) {
    v2f r; r.x = dppmul<CTRL>(v.x); r.y = dppmul<CTRL>(v.y); return r;
}
__device__ __forceinline__ v2f clamp01(v2f v) {
    v = __builtin_elementwise_max(v, (v2f)0.0f);
    return __builtin_elementwise_min(v, (v2f)1.0f);
}
// t = m*(x-1)+1  ==  m*x + (1-m)
#define TERM(mm, e) __builtin_elementwise_fma((mm), (v2f){(e), (e)}, (v2f){1.0f, 1.0f})

__global__ __launch_bounds__(256, 4)
void nmu_fwd(const float* __restrict__ x, const float* __restrict__ M,
             float* __restrict__ y)
{
    __shared__ __align__(16) float xt[2][TR * D];            // 2 x 4 KB
    __shared__ __align__(16) float part[ROWS_PB * 4 * O];    // 8 KB
    const int tid  = threadIdx.x;
    const int lane = tid & 63;
    const int w    = tid >> 6;       // wave = d-quarter
    const int ds   = lane & 7;       // 8-d subslice (half-row DPP group)
    const int oq   = lane >> 3;      // o-quad
    const int row0 = blockIdx.x * ROWS_PB;

    // ---- resident clamped M slice: d = w*64+ds*8+dd, o = oq*4..oq*4+3 ----
    const float2* M2 = reinterpret_cast<const float2*>(M);
    const int mb = (w * 64 + ds * 8) * (O / 2) + oq * 2;     // float2 index
#define MLOAD(dd) \
    float2 l##dd = M2[mb + (dd) * 16]; float2 h##dd = M2[mb + (dd) * 16 + 1]; \
    v2f mL##dd = clamp01((v2f){l##dd.x, l##dd.y});                            \
    v2f mH##dd = clamp01((v2f){h##dd.x, h##dd.y});
    MLOAD(0) MLOAD(1) MLOAD(2) MLOAD(3) MLOAD(4) MLOAD(5) MLOAD(6) MLOAD(7)
#undef MLOAD

    // ---- pipelined x staging: tile t = rows t*4..t*4+3, 1 f4 per thread ----
    const float4* xg = reinterpret_cast<const float4*>(x + row0 * D);
    float4 hold = xg[tid];                                   // tile 0
    reinterpret_cast<float4*>(xt[0])[tid] = hold;
    __syncthreads();

    const int xoff = w * 16 + ds * 2;                        // f4 idx in row
#pragma unroll
    for (int t = 0; t < NT; ++t) {
        if (t + 1 < NT) hold = xg[(t + 1) * 256 + tid];      // overlap compute
        const float4* lt = reinterpret_cast<const float4*>(xt[t & 1]);

#pragma unroll
        for (int rr = 0; rr < TR; ++rr) {
            const float4 xa = lt[rr * 64 + xoff];            // ds_read_b128
            const float4 xb = lt[rr * 64 + xoff + 1];
            const float e0 = xa.x - 1.0f, e1 = xa.y - 1.0f;
            const float e2 = xa.z - 1.0f, e3 = xa.w - 1.0f;
            const float e4 = xb.x - 1.0f, e5 = xb.y - 1.0f;
            const float e6 = xb.z - 1.0f, e7 = xb.w - 1.0f;

            v2f pL = (TERM(mL0, e0) * TERM(mL1, e1)) * (TERM(mL2, e2) * TERM(mL3, e3));
            pL    *= (TERM(mL4, e4) * TERM(mL5, e5)) * (TERM(mL6, e6) * TERM(mL7, e7));
            v2f pH = (TERM(mH0, e0) * TERM(mH1, e1)) * (TERM(mH2, e2) * TERM(mH3, e3));
            pH    *= (TERM(mH4, e4) * TERM(mH5, e5)) * (TERM(mH6, e6) * TERM(mH7, e7));

            // product across 8 ds-lanes: quad xor1, xor2, half-row mirror
            pL = dppmul2<0xB1>(pL); pL = dppmul2<0x4E>(pL); pL = dppmul2<0x141>(pL);
            pH = dppmul2<0xB1>(pH); pH = dppmul2<0x4E>(pH); pH = dppmul2<0x141>(pH);

            if (ds == 0) {                                   // 8 lanes/wave
                float4 pv = {pL.x, pL.y, pH.x, pH.y};
                const int r = t * TR + rr;
                *reinterpret_cast<float4*>(&part[(r * 4 + w) * O + oq * 4]) = pv;
            }
        }

        if (t + 1 < NT)                                      // waits vmcnt here
            reinterpret_cast<float4*>(xt[(t + 1) & 1])[tid] = hold;
        __syncthreads();
    }

    // ---- merge 4 quarter-partials; 256 threads = 16 rows x 16 o-pairs ----
    {
        const int mr = tid >> 4;
        const int op = tid & 15;
        const v2f* pp = reinterpret_cast<const v2f*>(part);
        v2f a = pp[(mr * 4 + 0) * (O / 2) + op] * pp[(mr * 4 + 1) * (O / 2) + op];
        v2f b = pp[(mr * 4 + 2) * (O / 2) + op] * pp[(mr * 4 + 3) * (O / 2) + op];
        a *= b;
        *reinterpret_cast<v2f*>(y + (row0 + mr) * O + op * 2) = a;  // 8B/lane
    }
}

extern "C" void kernel_launch(void* const* d_in, const int* in_sizes, int n_in,
                              void* d_out, int out_size, void* d_ws, size_t ws_size,
                              hipStream_t stream) {
    const float* x = (const float*)d_in[0];   // [16384, 256]
    const float* M = (const float*)d_in[1];   // [256, 32]
    float* y = (float*)d_out;                 // [16384, 32]
    const int B = in_sizes[0] / D;            // 16384
    dim3 grid(B / ROWS_PB);                   // 1024 blocks = 4 per CU
    nmu_fwd<<<grid, 256, 0, stream>>>(x, M, y);
}